// Round 11
// baseline (517.784 us; speedup 1.0000x reference)
//
#include <hip/hip_runtime.h>
#include <math.h>

#define BB 8
#define SS 2000
#define DMM 512
#define HHN 4
#define DKK 512
#define HDK 2048
#define NLL 32
#define HNL 128
#define GGN 200
#define WSZ 10
#define TTN 20
#define EXTT 5
#define MMR (BB*SS)   // 16000

typedef unsigned short bf16_t;
typedef __attribute__((ext_vector_type(8))) short short8;
typedef __attribute__((ext_vector_type(4))) float floatx4;

// async global->LDS, 16B per lane. LDS dest must be wave-uniform-base + lane*16
// (linear); any swizzle must be applied to the GLOBAL source address.
#define GLL16(gp, lp) __builtin_amdgcn_global_load_lds( \
    (__attribute__((address_space(1))) void*)(gp), \
    (__attribute__((address_space(3))) void*)(lp), 16, 0, 0)

__device__ __forceinline__ float bf2f(bf16_t u) {
  union { unsigned u; float f; } x; x.u = ((unsigned)u) << 16; return x.f;
}
__device__ __forceinline__ bf16_t f2bf(float f) {
  union { float f; unsigned u; } x; x.f = f;
  unsigned r = x.u + 0x7FFFu + ((x.u >> 16) & 1u);
  return (bf16_t)(r >> 16);
}

// ---------------- block reduction helper (256 threads) ----------------
__device__ __forceinline__ float block_sum256(float v, float* sh) {
  #pragma unroll
  for (int off = 32; off > 0; off >>= 1) v += __shfl_down(v, off);
  if ((threadIdx.x & 63) == 0) sh[threadIdx.x >> 6] = v;
  __syncthreads();
  float t = sh[0] + sh[1] + sh[2] + sh[3];
  __syncthreads();
  return t;
}

// ---------------- X fp32 -> bf16 (once; feeds all projections) --------------
__global__ __launch_bounds__(256)
void x_to_bf16(const float* __restrict__ X, bf16_t* __restrict__ Xb) {
  int i = blockIdx.x * 256 + threadIdx.x;   // 8 elements per thread
  float4 a = *(const float4*)&X[(size_t)i * 8];
  float4 b = *(const float4*)&X[(size_t)i * 8 + 4];
  ushort4 u0, u1;
  u0.x = f2bf(a.x); u0.y = f2bf(a.y); u0.z = f2bf(a.z); u0.w = f2bf(a.w);
  u1.x = f2bf(b.x); u1.y = f2bf(b.y); u1.z = f2bf(b.z); u1.w = f2bf(b.w);
  *(ushort4*)&Xb[(size_t)i * 8] = u0;
  *(ushort4*)&Xb[(size_t)i * 8 + 4] = u1;
}

// ---------------- weight transpose fp32 -> bf16 B^T (generic) ---------------
__global__ __launch_bounds__(256)
void transpose_w(const float* __restrict__ W, bf16_t* __restrict__ Wt,
                 int K, int N) {
  __shared__ float Ts[64][65];
  int n0 = blockIdx.x * 64, k0 = blockIdx.y * 64;
  int tid = threadIdx.x;
  #pragma unroll
  for (int i = 0; i < 16; ++i) {
    int e = i * 256 + tid;
    int r = e >> 6, c = e & 63;
    Ts[r][c] = W[(size_t)(k0 + r) * N + n0 + c];
  }
  __syncthreads();
  #pragma unroll
  for (int i = 0; i < 16; ++i) {
    int e = i * 256 + tid;
    int r = e >> 6, c = e & 63;
    Wt[(size_t)(n0 + r) * K + k0 + c] = f2bf(Ts[c][r]);
  }
}

// ---------------- fused transpose of Wq|Wk|Wv into one [6144][512] B^T ------
// grid (32, 24): by selects source (by>>3) and k-chunk (by&7).
__global__ __launch_bounds__(256)
void transpose_wqkv(const float* __restrict__ Wq, const float* __restrict__ Wk,
                    const float* __restrict__ Wv, bf16_t* __restrict__ Wt) {
  __shared__ float Ts[64][65];
  int by = blockIdx.y;
  int which = by >> 3;
  const float* W = which == 0 ? Wq : (which == 1 ? Wk : Wv);
  int k0 = (by & 7) * 64;
  int n0 = blockIdx.x * 64;
  int tid = threadIdx.x;
  #pragma unroll
  for (int i = 0; i < 16; ++i) {
    int e = i * 256 + tid;
    int r = e >> 6, c = e & 63;
    Ts[r][c] = W[(size_t)(k0 + r) * 2048 + n0 + c];
  }
  __syncthreads();
  #pragma unroll
  for (int i = 0; i < 16; ++i) {
    int e = i * 256 + tid;
    int r = e >> 6, c = e & 63;
    Wt[(size_t)(which * 2048 + n0 + r) * 512 + k0 + c] = f2bf(Ts[c][r]);
  }
}

// ---------------- bf16 MFMA GEMM with global_load_lds staging (BK=32) -------
// Out = (A[M,K]bf16 @ Bt[N,K]^T + bias) * alpha. 128x128 tile.
// KEPT AT BK=32 as the control for this round's BK=64 experiment in qkvh.
template <typename TO>
__global__ __launch_bounds__(256)
void gemm_bf16(const bf16_t* __restrict__ A, const bf16_t* __restrict__ Bt,
               const float* __restrict__ bias, TO* __restrict__ Cout,
               int M, int N, int K, float alpha) {
  __shared__ bf16_t As[128 * 32];
  __shared__ bf16_t Bs[128 * 32];
  int tid = threadIdx.x;
  int wave = tid >> 6, lane = tid & 63;
  int wr = wave >> 1, wc = wave & 1;
  int quad = lane >> 4, ml = lane & 15;
  int bm = blockIdx.y * 128, bn = blockIdx.x * 128;

  floatx4 acc[4][4];
  #pragma unroll
  for (int i = 0; i < 4; ++i)
    #pragma unroll
    for (int j = 0; j < 4; ++j)
      #pragma unroll
      for (int r = 0; r < 4; ++r) acc[i][j][r] = 0.f;

  int lin0 = wave * 64 + lane;
  int lin1 = 256 + lin0;
  int row0 = lin0 >> 2, ch0 = (lin0 & 3) ^ ((row0 >> 1) & 3);
  int row1 = lin1 >> 2, ch1 = (lin1 & 3) ^ ((row1 >> 1) & 3);
  const bf16_t* gA0 = &A[(size_t)(bm + row0) * K + ch0 * 8];
  const bf16_t* gA1 = &A[(size_t)(bm + row1) * K + ch1 * 8];
  const bf16_t* gB0 = &Bt[(size_t)(bn + row0) * K + ch0 * 8];
  const bf16_t* gB1 = &Bt[(size_t)(bn + row1) * K + ch1 * 8];

  for (int k0 = 0; k0 < K; k0 += 32) {
    GLL16(gA0 + k0, &As[lin0 * 8]);
    GLL16(gA1 + k0, &As[lin1 * 8]);
    GLL16(gB0 + k0, &Bs[lin0 * 8]);
    GLL16(gB1 + k0, &Bs[lin1 * 8]);
    __syncthreads();
    short8 af[4], bfr[4];
    #pragma unroll
    for (int i = 0; i < 4; ++i) {
      int row = wr * 64 + i * 16 + ml;
      int sw = quad ^ ((row >> 1) & 3);
      af[i] = *(const short8*)&As[row * 32 + sw * 8];
    }
    #pragma unroll
    for (int j = 0; j < 4; ++j) {
      int row = wc * 64 + j * 16 + ml;
      int sw = quad ^ ((row >> 1) & 3);
      bfr[j] = *(const short8*)&Bs[row * 32 + sw * 8];
    }
    #pragma unroll
    for (int i = 0; i < 4; ++i)
      #pragma unroll
      for (int j = 0; j < 4; ++j)
        acc[i][j] = __builtin_amdgcn_mfma_f32_16x16x32_bf16(af[i], bfr[j], acc[i][j], 0, 0, 0);
    __syncthreads();
  }
  #pragma unroll
  for (int i = 0; i < 4; ++i) {
    int row0o = bm + wr * 64 + i * 16 + quad * 4;
    #pragma unroll
    for (int j = 0; j < 4; ++j) {
      int col = bn + wc * 64 + j * 16 + ml;
      float bv = bias[col];
      #pragma unroll
      for (int r = 0; r < 4; ++r) {
        float o = (acc[i][j][r] + bv) * alpha;
        if constexpr (sizeof(TO) == 2)
          Cout[(size_t)(row0o + r) * N + col] = f2bf(o);
        else
          Cout[(size_t)(row0o + r) * N + col] = o;
      }
    }
  }
}

// ---------------- fused QKV + hs projection, BK=64, balanced 1D grid --------
// Bt rows: 0..2047 Wq^T | 2048..4095 Wk^T | 4096..6143 Wv^T | 6144..6271 Wd^T.
// Grid = 6125 blocks, 1D (R8 layout: bid<6000 -> QKV bx=bid%48, by=bid/48;
// 48%8==0 keeps per-XCD B-panel affinity; bid>=6000 -> hs row-blocks).
// BK=64: halves barrier count (32->16), doubles MFMA per barrier interval,
// amortizing the 2-phase drain stall. LDS 32 KB -> 5 blocks/CU.
// Bank scheme (row = 128 B = bank width, so rows are bank-neutral):
//   store slot = chunk ^ (row&7)  (applied on GLOBAL source; LDS linear)
//   read  slot = (ks*4+quad) ^ (row&7)
// Per 16-lane phase (fixed ks,quad): ml=0..15 hits all 8 bank-quads twice
// (2-way = free) -- same per-phase coverage as the verified BK=32 scheme.
__global__ __launch_bounds__(256)
void gemm_qkvh(const bf16_t* __restrict__ A, const bf16_t* __restrict__ Bt,
               const float* __restrict__ bq, const float* __restrict__ bk,
               const float* __restrict__ bv, const float* __restrict__ bd,
               bf16_t* __restrict__ Qo, bf16_t* __restrict__ Ko,
               bf16_t* __restrict__ Vo, float* __restrict__ hso, float scale) {
  const int K = 512;
  __shared__ bf16_t As[128 * 64];
  __shared__ bf16_t Bs[128 * 64];
  int tid = threadIdx.x;
  int wave = tid >> 6, lane = tid & 63;
  int wr = wave >> 1, wc = wave & 1;
  int quad = lane >> 4, ml = lane & 15;

  int bid = blockIdx.x;
  int bm, bn;
  if (bid < 6000) {
    bn = (bid % 48) * 128;
    bm = (bid / 48) * 128;
  } else {
    bn = 6144;
    bm = (bid - 6000) * 128;
  }
  int nb = bn >> 11;
  const float* bias = nb == 0 ? bq : (nb == 1 ? bk : (nb == 2 ? bv : bd));
  bf16_t* Cb = nb == 0 ? Qo : (nb == 1 ? Ko : Vo);
  float alpha = nb == 0 ? scale : 1.f;
  int bcol = bn & 2047;

  floatx4 acc[4][4];
  #pragma unroll
  for (int i = 0; i < 4; ++i)
    #pragma unroll
    for (int j = 0; j < 4; ++j)
      #pragma unroll
      for (int r = 0; r < 4; ++r) acc[i][j][r] = 0.f;

  // staging map: 4 passes of 256 lanes; lin in [0,1024) = 128 rows x 8 chunks
  int lin0 = 0 * 256 + tid, lin1 = 1 * 256 + tid;
  int lin2 = 2 * 256 + tid, lin3 = 3 * 256 + tid;
  int r0 = lin0 >> 3, c0 = (lin0 & 7) ^ (r0 & 7);
  int r1 = lin1 >> 3, c1 = (lin1 & 7) ^ (r1 & 7);
  int r2 = lin2 >> 3, c2 = (lin2 & 7) ^ (r2 & 7);
  int r3 = lin3 >> 3, c3 = (lin3 & 7) ^ (r3 & 7);
  const bf16_t* gA0 = &A[(size_t)(bm + r0) * K + c0 * 8];
  const bf16_t* gA1 = &A[(size_t)(bm + r1) * K + c1 * 8];
  const bf16_t* gA2 = &A[(size_t)(bm + r2) * K + c2 * 8];
  const bf16_t* gA3 = &A[(size_t)(bm + r3) * K + c3 * 8];
  const bf16_t* gB0 = &Bt[(size_t)(bn + r0) * K + c0 * 8];
  const bf16_t* gB1 = &Bt[(size_t)(bn + r1) * K + c1 * 8];
  const bf16_t* gB2 = &Bt[(size_t)(bn + r2) * K + c2 * 8];
  const bf16_t* gB3 = &Bt[(size_t)(bn + r3) * K + c3 * 8];

  for (int k0 = 0; k0 < K; k0 += 64) {
    GLL16(gA0 + k0, &As[lin0 * 8]);
    GLL16(gA1 + k0, &As[lin1 * 8]);
    GLL16(gA2 + k0, &As[lin2 * 8]);
    GLL16(gA3 + k0, &As[lin3 * 8]);
    GLL16(gB0 + k0, &Bs[lin0 * 8]);
    GLL16(gB1 + k0, &Bs[lin1 * 8]);
    GLL16(gB2 + k0, &Bs[lin2 * 8]);
    GLL16(gB3 + k0, &Bs[lin3 * 8]);
    __syncthreads();
    #pragma unroll
    for (int ks = 0; ks < 2; ++ks) {
      short8 af[4], bfr[4];
      #pragma unroll
      for (int i = 0; i < 4; ++i) {
        int rowA = wr * 64 + i * 16 + ml;
        int slA = (ks * 4 + quad) ^ (rowA & 7);
        af[i] = *(const short8*)&As[rowA * 64 + slA * 8];
        int rowB = wc * 64 + i * 16 + ml;
        int slB = (ks * 4 + quad) ^ (rowB & 7);
        bfr[i] = *(const short8*)&Bs[rowB * 64 + slB * 8];
      }
      #pragma unroll
      for (int i = 0; i < 4; ++i)
        #pragma unroll
        for (int j = 0; j < 4; ++j)
          acc[i][j] = __builtin_amdgcn_mfma_f32_16x16x32_bf16(af[i], bfr[j], acc[i][j], 0, 0, 0);
    }
    __syncthreads();
  }
  #pragma unroll
  for (int i = 0; i < 4; ++i) {
    int row0o = bm + wr * 64 + i * 16 + quad * 4;
    #pragma unroll
    for (int j = 0; j < 4; ++j) {
      int col = bcol + wc * 64 + j * 16 + ml;
      float bv2 = bias[col];
      #pragma unroll
      for (int r = 0; r < 4; ++r) {
        float o = (acc[i][j][r] + bv2) * alpha;
        if (nb == 3) hso[(size_t)(row0o + r) * HNL + col] = o;
        else         Cb[(size_t)(row0o + r) * HDK + col] = f2bf(o);
      }
    }
  }
}

// ---------------- LayerNorm over bf16 rows of 2048 (in place) ---------------
// K and V are contiguous -> one launch with 2*MMR blocks covers both.
__global__ __launch_bounds__(256)
void ln2048_bf16(bf16_t* __restrict__ Y, const float* __restrict__ gam,
                 const float* __restrict__ bet) {
  __shared__ float sh[4];
  bf16_t* y = Y + (size_t)blockIdx.x * HDK;
  int t = threadIdx.x;
  ushort4 ra = *(const ushort4*)&y[t * 8];
  ushort4 rb = *(const ushort4*)&y[t * 8 + 4];
  float v[8];
  v[0] = bf2f(ra.x); v[1] = bf2f(ra.y); v[2] = bf2f(ra.z); v[3] = bf2f(ra.w);
  v[4] = bf2f(rb.x); v[5] = bf2f(rb.y); v[6] = bf2f(rb.z); v[7] = bf2f(rb.w);
  float s = 0.f;
  #pragma unroll
  for (int j = 0; j < 8; ++j) s += v[j];
  s = block_sum256(s, sh);
  float mean = s * (1.f / 2048.f);
  float ss = 0.f;
  #pragma unroll
  for (int j = 0; j < 8; ++j) { float d = v[j] - mean; ss = fmaf(d, d, ss); }
  ss = block_sum256(ss, sh);
  float rstd = rsqrtf(ss * (1.f / 2048.f) + 1e-5f);
  float gg[8], bb[8];
  *(float4*)&gg[0] = *(const float4*)&gam[t * 8];
  *(float4*)&gg[4] = *(const float4*)&gam[t * 8 + 4];
  *(float4*)&bb[0] = *(const float4*)&bet[t * 8];
  *(float4*)&bb[4] = *(const float4*)&bet[t * 8 + 4];
  ushort4 oa, ob;
  oa.x = f2bf((v[0] - mean) * rstd * gg[0] + bb[0]);
  oa.y = f2bf((v[1] - mean) * rstd * gg[1] + bb[1]);
  oa.z = f2bf((v[2] - mean) * rstd * gg[2] + bb[2]);
  oa.w = f2bf((v[3] - mean) * rstd * gg[3] + bb[3]);
  ob.x = f2bf((v[4] - mean) * rstd * gg[4] + bb[4]);
  ob.y = f2bf((v[5] - mean) * rstd * gg[5] + bb[5]);
  ob.z = f2bf((v[6] - mean) * rstd * gg[6] + bb[6]);
  ob.w = f2bf((v[7] - mean) * rstd * gg[7] + bb[7]);
  *(ushort4*)&y[t * 8] = oa;
  *(ushort4*)&y[t * 8 + 4] = ob;
}

// ---------------- column sums of exp(hs) over valid s -----------------------
__global__ __launch_bounds__(256)
void hs_colsum(const float* __restrict__ hs, const float* __restrict__ mask,
               float* __restrict__ Ssum) {
  __shared__ float red[128];
  int b = blockIdx.x / 100;
  int chunk = blockIdx.x % 100;
  int tid = threadIdx.x;
  int c = tid & 127, half = tid >> 7;
  int s0 = chunk * 20;
  float sum = 0.f;
  #pragma unroll
  for (int i = 0; i < 10; ++i) {
    int s = s0 + i * 2 + half;
    float m = mask[(size_t)b * SS + s];
    float v = hs[((size_t)b * SS + s) * HNL + c];
    sum += (m != 0.f) ? __expf(v) : 0.f;
  }
  if (half == 1) red[c] = sum;
  __syncthreads();
  if (half == 0) atomicAdd(&Ssum[b * HNL + c], sum + red[c]);
}

// ---------------- landmark compression via MFMA -----------------------------
__global__ __launch_bounds__(256)
void compress_mfma(const bf16_t* __restrict__ Kf, const bf16_t* __restrict__ Vf,
                   const float* __restrict__ hs, const float* __restrict__ mask,
                   const float* __restrict__ Ssum, float* __restrict__ Kc,
                   float* __restrict__ Vc) {
  int dch = blockIdx.x & 3;
  int sch = (blockIdx.x >> 2) & 7;
  int bh  = blockIdx.x >> 5;
  int h = bh & 3, b = bh >> 2;
  int sbase = sch * 250;
  int dbase = dch * 128;

  __shared__ __align__(16) bf16_t Ah[32 * 40];
  __shared__ __align__(16) bf16_t Kt[128 * 40];
  __shared__ __align__(16) bf16_t Vt[128 * 40];

  int tid = threadIdx.x;
  int wave = tid >> 6, lane = tid & 63;
  int tensor = wave >> 1, nh = wave & 1;
  int quad = lane >> 4, ml = lane & 15;

  float inv8[8];
  if (tid < 128) {
    int l0 = (tid & 3) * 8;
    #pragma unroll
    for (int j = 0; j < 8; ++j)
      inv8[j] = 1.f / Ssum[b * HNL + h * NLL + l0 + j];
  }

  floatx4 acc[2][4];
  #pragma unroll
  for (int i = 0; i < 2; ++i)
    #pragma unroll
    for (int j = 0; j < 4; ++j)
      #pragma unroll
      for (int r = 0; r < 4; ++r) acc[i][j][r] = 0.f;

  for (int ks = 0; ks < 8; ++ks) {
    int s0 = ks * 32;
    if (tid < 128) {
      int si = tid >> 2;
      int l0 = (tid & 3) * 8;
      int s_l = s0 + si;
      float w[8];
      #pragma unroll
      for (int j = 0; j < 8; ++j) w[j] = 0.f;
      if (s_l < 250) {
        float m = mask[(size_t)b * SS + sbase + s_l];
        if (m != 0.f) {
          const float* p = &hs[((size_t)b * SS + sbase + s_l) * HNL + h * NLL + l0];
          float4 f0 = *(const float4*)p;
          float4 f1 = *(const float4*)(p + 4);
          w[0] = __expf(f0.x) * inv8[0];
          w[1] = __expf(f0.y) * inv8[1];
          w[2] = __expf(f0.z) * inv8[2];
          w[3] = __expf(f0.w) * inv8[3];
          w[4] = __expf(f1.x) * inv8[4];
          w[5] = __expf(f1.y) * inv8[5];
          w[6] = __expf(f1.z) * inv8[6];
          w[7] = __expf(f1.w) * inv8[7];
        }
      }
      #pragma unroll
      for (int j = 0; j < 8; ++j)
        Ah[(l0 + j) * 40 + si] = f2bf(w[j]);
    }
    {
      int si = tid >> 3;
      int d0 = (tid & 7) * 16;
      int s_l = s0 + si;
      uint4 ka = {0, 0, 0, 0}, kb = {0, 0, 0, 0};
      uint4 va = {0, 0, 0, 0}, vb = {0, 0, 0, 0};
      if (s_l < 250) {
        size_t gof = ((size_t)b * SS + sbase + s_l) * HDK + h * DKK + dbase + d0;
        ka = *(const uint4*)&Kf[gof];
        kb = *(const uint4*)&Kf[gof + 8];
        va = *(const uint4*)&Vf[gof];
        vb = *(const uint4*)&Vf[gof + 8];
      }
      const ushort* kp = (const ushort*)&ka;
      const ushort* kq = (const ushort*)&kb;
      const ushort* vp = (const ushort*)&va;
      const ushort* vq = (const ushort*)&vb;
      #pragma unroll
      for (int j = 0; j < 8; ++j) {
        Kt[(d0 + j) * 40 + si]     = kp[j];
        Kt[(d0 + 8 + j) * 40 + si] = kq[j];
        Vt[(d0 + j) * 40 + si]     = vp[j];
        Vt[(d0 + 8 + j) * 40 + si] = vq[j];
      }
    }
    __syncthreads();
    const bf16_t* Bsel = tensor ? Vt : Kt;
    #pragma unroll
    for (int i = 0; i < 2; ++i) {
      short8 af = *(const short8*)&Ah[(i * 16 + ml) * 40 + quad * 8];
      #pragma unroll
      for (int j = 0; j < 4; ++j) {
        short8 bfr = *(const short8*)&Bsel[(nh * 64 + j * 16 + ml) * 40 + quad * 8];
        acc[i][j] = __builtin_amdgcn_mfma_f32_16x16x32_bf16(af, bfr, acc[i][j], 0, 0, 0);
      }
    }
    __syncthreads();
  }
  float* outp = tensor ? Vc : Kc;
  size_t obase = ((size_t)b * 4 + h) * (NLL * DKK);
  #pragma unroll
  for (int i = 0; i < 2; ++i) {
    #pragma unroll
    for (int j = 0; j < 4; ++j) {
      int d = dbase + nh * 64 + j * 16 + ml;
      #pragma unroll
      for (int r = 0; r < 4; ++r) {
        int l = i * 16 + quad * 4 + r;
        atomicAdd(&outp[obase + (size_t)l * DKK + d], acc[i][j][r]);
      }
    }
  }
}

// ---------------- LN on Kc AND Vc rows (merged), bf16 out -------------------
__global__ __launch_bounds__(256)
void ln_comp_both(const float* __restrict__ Kc, const float* __restrict__ Vc,
                  const float* __restrict__ gam, const float* __restrict__ bet,
                  bf16_t* __restrict__ KcB, bf16_t* __restrict__ VcT) {
  __shared__ float sh[4];
  int which = blockIdx.x >> 8;
  int bid = blockIdx.x & 255;
  const float* Y = which ? Vc : Kc;
  bf16_t* outp = which ? VcT : KcB;
  int b = bid >> 5, l = bid & 31;
  size_t base = (size_t)b * 65536 + (size_t)l * 512;
  float v[8]; float s = 0.f;
  #pragma unroll
  for (int j = 0; j < 8; ++j) {
    int f = threadIdx.x + 256 * j;
    int hh = f >> 9, dd = f & 511;
    v[j] = Y[base + (size_t)hh * 16384 + dd];
    s += v[j];
  }
  s = block_sum256(s, sh);
  float mean = s * (1.f / 2048.f);
  float ss = 0.f;
  #pragma unroll
  for (int j = 0; j < 8; ++j) { float d = v[j] - mean; ss = fmaf(d, d, ss); }
  ss = block_sum256(ss, sh);
  float rstd = rsqrtf(ss * (1.f / 2048.f) + 1e-5f);
  #pragma unroll
  for (int j = 0; j < 8; ++j) {
    int f = threadIdx.x + 256 * j;
    int hh = f >> 9, dd = f & 511;
    float o = (v[j] - mean) * rstd * gam[f] + bet[f];
    if (!which)
      outp[(((size_t)b * 4 + hh) * 32 + l) * 512 + dd] = f2bf(o);
    else
      outp[(((size_t)b * 4 + hh) * 512 + dd) * 32 + l] = f2bf(o);
  }
}

// ---------------- MFMA fused attention v4: no transpose buffer --------------
__global__ __launch_bounds__(256)
void attn_mfma4(const bf16_t* __restrict__ Qf, const bf16_t* __restrict__ Kf,
                const bf16_t* __restrict__ Vf, const bf16_t* __restrict__ KcB,
                const bf16_t* __restrict__ VcT, const float* __restrict__ mask,
                bf16_t* __restrict__ Cf) {
  int gp = blockIdx.x % 100;
  int bh = blockIdx.x / 100;
  int h = bh & 3, b = bh >> 2;
  int g0row = gp * 20;
  int wbase = g0row - EXTT;

  __shared__ bf16_t Vst[30 * 128];   //  7680 B, chunk-swizzled
  __shared__ float  sc[20][68];      //  5440 B raw scores
  __shared__ bf16_t Ps[32 * 88];     //  5632 B bf16 probs (compress|window)
  __shared__ float  cv[32];          //  total ~18.9 KB -> 8 blocks/CU

  int tid = threadIdx.x;
  int wave = tid >> 6, lane = tid & 63;
  int quad = lane >> 4, ml = lane & 15;

  if (tid < 30) {
    int j = wbase + tid;
    cv[tid] = (j >= 0 && j < SS && mask[(size_t)b * SS + j] != 0.f) ? 1.f : 0.f;
  }
  for (int i = tid; i < 32 * 88; i += 256) Ps[i] = 0;

  // ---- scores: direct-global MFMA ----
  int qr0 = g0row + (ml < 20 ? ml : 19);
  int r1c = 16 + ml;
  int qr1 = g0row + (r1c < 20 ? r1c : 19);
  const bf16_t* ap0 = Qf + ((size_t)b * SS + qr0) * HDK + h * DKK;
  const bf16_t* ap1 = Qf + ((size_t)b * SS + qr1) * HDK + h * DKK;
  int brow = wave * 16 + ml;
  const bf16_t* bp;
  if (brow < 32) {
    bp = KcB + ((size_t)bh * 32 + brow) * 512;
  } else {
    int j = wbase + brow - 32;
    j = j < 0 ? 0 : (j >= SS ? SS - 1 : j);
    bp = Kf + ((size_t)b * SS + j) * HDK + h * DKK;
  }
  floatx4 s0 = {0.f, 0.f, 0.f, 0.f}, s1 = {0.f, 0.f, 0.f, 0.f};
  #pragma unroll 8
  for (int ks = 0; ks < 16; ++ks) {
    short8 af0 = *(const short8*)(ap0 + ks * 32 + quad * 8);
    short8 af1 = *(const short8*)(ap1 + ks * 32 + quad * 8);
    short8 bfr = *(const short8*)(bp  + ks * 32 + quad * 8);
    s0 = __builtin_amdgcn_mfma_f32_16x16x32_bf16(af0, bfr, s0, 0, 0, 0);
    s1 = __builtin_amdgcn_mfma_f32_16x16x32_bf16(af1, bfr, s1, 0, 0, 0);
  }
  #pragma unroll
  for (int r = 0; r < 4; ++r) {
    int row0 = quad * 4 + r;
    if (row0 < 20) sc[row0][wave * 16 + ml] = s0[r];
    int row1 = 16 + quad * 4 + r;
    if (row1 < 20) sc[row1][wave * 16 + ml] = s1[r];
  }

  // ---- V chunk 0 prefetch (overlaps barrier + softmax) ----
  uint4 vr[2];
  #pragma unroll
  for (int vi = 0; vi < 2; ++vi) {
    int idx = vi * 256 + tid;
    uint4 z = {0, 0, 0, 0};
    if (idx < 480) {
      int u = idx >> 4, c8 = idx & 15;
      int j = wbase + u;
      if (j >= 0 && j < SS)
        z = *(const uint4*)&Vf[((size_t)b * SS + j) * HDK + h * DKK + c8 * 8];
    }
    vr[vi] = z;
  }
  __syncthreads();   // B1: sc, Ps-zero, cv visible

  // ---- softmax: 160 threads, 8 per row ----
  if (tid < 160) {
    int r = tid >> 3, part = tid & 7;
    float mx = -INFINITY;
    #pragma unroll
    for (int i = 0; i < 8; ++i) {
      int c = part + i * 8;
      if (c < 62) {
        float v = sc[r][c];
        bool valid;
        if (c < 32) valid = true;
        else {
          int u = c - 32;
          valid = (u < 30) && (cv[u] != 0.f) && (r < 10 ? (u < 20) : (u >= 10));
        }
        v = valid ? v : -INFINITY;
        sc[r][c] = v;
        mx = fmaxf(mx, v);
      }
    }
    mx = fmaxf(mx, __shfl_xor(mx, 1));
    mx = fmaxf(mx, __shfl_xor(mx, 2));
    mx = fmaxf(mx, __shfl_xor(mx, 4));
    float sum = 0.f;
    #pragma unroll
    for (int i = 0; i < 8; ++i) {
      int c = part + i * 8;
      if (c < 62) {
        float e = expf(sc[r][c] - mx);
        sc[r][c] = e;
        sum += e;
      }
    }
    sum += __shfl_xor(sum, 1);
    sum += __shfl_xor(sum, 2);
    sum += __shfl_xor(sum, 4);
    float qm = mask[(size_t)b * SS + g0row + r];
    float inv = (qm != 0.f) ? 1.f / sum : 0.f;
    #pragma unroll
    for (int i = 0; i < 8; ++i) {
      int c = part + i * 8;
      if (c < 62) {
        float p = sc[r][c] * inv;
        if (c < 32) Ps[r * 88 + c] = f2bf(p);
        else        Ps[r * 88 + 40 + (c - 32)] = f2bf(p);
      }
    }
  }
  // write Vst chunk 0 (swizzled slots)
  #pragma unroll
  for (int vi = 0; vi < 2; ++vi) {
    int idx = vi * 256 + tid;
    if (idx < 480) {
      int u = idx >> 4, c8 = idx & 15;
      int slot = c8 ^ ((u >> 3) & 3);
      *(uint4*)&Vst[u * 128 + slot * 8] = vr[vi];
    }
  }
  __syncthreads();   // B2: Vst0 ready, softmax done

  // ---- P fragments (persist across chunks) ----
  short8 pac0 = *(const short8*)&Ps[ml * 88 + quad * 8];
  short8 pac1 = *(const short8*)&Ps[(16 + ml) * 88 + quad * 8];
  short8 paw0 = *(const short8*)&Ps[ml * 88 + 40 + quad * 8];
  short8 paw1 = *(const short8*)&Ps[(16 + ml) * 88 + 40 + quad * 8];
  size_t vctbase = ((size_t)bh * 512) * 32;
  size_t cbase = ((size_t)b * SS + g0row) * HDK + h * DKK;

  // ---- chunked PV straight from swizzled Vst columns ----
  #pragma unroll
  for (int ch = 0; ch < 4; ++ch) {
    int dA = ch * 128 + (wave * 2 + 0) * 16 + ml;
    int dB = ch * 128 + (wave * 2 + 1) * 16 + ml;
    short8 vcfA = *(const short8*)&VcT[vctbase + (size_t)dA * 32 + quad * 8];
    short8 vcfB = *(const short8*)&VcT[vctbase + (size_t)dB * 32 + quad * 8];
    if (ch < 3) {
      #pragma unroll
      for (int vi = 0; vi < 2; ++vi) {
        int idx = vi * 256 + tid;
        uint4 z = {0, 0, 0, 0};
        if (idx < 480) {
          int u = idx >> 4, c8 = idx & 15;
          int j = wbase + u;
          if (j >= 0 && j < SS)
            z = *(const uint4*)&Vf[((size_t)b * SS + j) * HDK + h * DKK + (ch + 1) * 128 + c8 * 8];
        }
        vr[vi] = z;
      }
    }

    #pragma unroll
    for (int half = 0; half < 2; ++half) {
      int dl = (wave * 2 + half) * 16 + ml;     // 0..127 within chunk
      int d = ch * 128 + dl;
      int cd = dl >> 3, de = dl & 7;
      short8 vwf;
      #pragma unroll
      for (int j = 0; j < 8; ++j) {
        int u = quad * 8 + j;                   // t index 0..31
        bf16_t x = 0;
        if (u < 30) {
          int slot = cd ^ ((u >> 3) & 3);
          x = Vst[u * 128 + slot * 8 + de];
        }
        vwf[j] = (short)x;
      }
      short8 vcf = half ? vcfB : vcfA;
      floatx4 o0 = {0.f, 0.f, 0.f, 0.f}, o1 = {0.f, 0.f, 0.f, 0.f};
      o0 = __builtin_amdgcn_mfma_f32_16x16x32_bf16(pac0, vcf, o0, 0, 0, 0);
      o0 = __builtin_amdgcn_mfma_f32_16x16x32_bf16(paw0, vwf, o0, 0, 0, 0);
      o1 = __builtin_amdgcn_mfma_f32_16x16x32_bf16(pac1, vcf, o1, 0, 0, 0);
      o1 = __builtin_amdgcn_mfma_f32_16x16x32_bf16(paw1, vwf, o1, 0, 0, 0);
      #pragma unroll
      for (int r = 0; r < 4; ++r) {
        int row0 = quad * 4 + r;
        if (row0 < 20) Cf[cbase + (size_t)row0 * HDK + d] = f2bf(o0[r]);
        int row1 = 16 + quad * 4 + r;
        if (row1 < 20) Cf[cbase + (size_t)row1 * HDK + d] = f2bf(o1[r]);
      }
    }
    __syncthreads();                   // PV(ch) done reading Vst
    if (ch < 3) {
      #pragma unroll
      for (int vi = 0; vi < 2; ++vi) {
        int idx = vi * 256 + tid;
        if (idx < 480) {
          int u = idx >> 4, c8 = idx & 15;
          int slot = c8 ^ ((u >> 3) & 3);
          *(uint4*)&Vst[u * 128 + slot * 8] = vr[vi];
        }
      }
      __syncthreads();                 // Vst(ch+1) ready
    }
  }
}

extern "C" void kernel_launch(void* const* d_in, const int* in_sizes, int n_in,
                              void* d_out, int out_size, void* d_ws, size_t ws_size,
                              hipStream_t stream) {
  const float* X     = (const float*)d_in[0];
  const float* mask  = (const float*)d_in[3];
  const float* Wq    = (const float*)d_in[4];
  const float* bq    = (const float*)d_in[5];
  const float* Wk    = (const float*)d_in[6];
  const float* bk    = (const float*)d_in[7];
  const float* Wv    = (const float*)d_in[8];
  const float* bv    = (const float*)d_in[9];
  const float* Wo    = (const float*)d_in[10];
  const float* bo    = (const float*)d_in[11];
  const float* Wd    = (const float*)d_in[12];
  const float* bd    = (const float*)d_in[13];
  const float* lnl_g = (const float*)d_in[14];
  const float* lnl_b = (const float*)d_in[15];
  const float* lns_g = (const float*)d_in[16];
  const float* lns_b = (const float*)d_in[17];
  float* out = (float*)d_out;

  // workspace carve (bytes): total ~209 MB
  char* ws = (char*)d_ws;
  bf16_t* Q   = (bf16_t*)(ws);                 // 65,536,000 B
  bf16_t* K   = (bf16_t*)(ws + 65536000);      // 65,536,000 B (V follows -> contiguous for merged LN)
  bf16_t* V   = (bf16_t*)(ws + 131072000);     // 65,536,000 B
  float*  hs  = (float*) (ws + 196608000);     // 8,192,000 B (raw, no softmax)
  float*  Kc  = (float*) (ws + 204800000);     // 2,097,152 B
  float*  Vc  = (float*) (ws + 206897152);     // 2,097,152 B
  bf16_t* C   = Q;                             // alias (see attn_mfma4 note)
  bf16_t* Wot = (bf16_t*)(ws + 65536000);      // K region (post-attn)
  // bf16 LN'd compress tensors in hs region (hs dead after compress).
  bf16_t* KcB = (bf16_t*)(ws + 196608000);            // 1,048,576 B
  bf16_t* VcT = (bf16_t*)(ws + 196608000 + 1048576);  // 1,048,576 B
  // d_out scratch (all dead before the final out-projection writes d_out):
  float*  Ssum  = (float*)d_out;                        // 4 KB at offset 0
  bf16_t* Xbf   = (bf16_t*)((char*)d_out + 65536);      // 16,384,000 B
  bf16_t* Wqkvt = (bf16_t*)((char*)d_out + 16449536);   // 6,291,456 B [6144][512]
  bf16_t* Wdt   = (bf16_t*)((char*)d_out + 22740992);   // 131,072 B, = Wqkvt rows 6144..6271
  // (ends at 22,872,064 < out_size 32,768,000)

  const float scale = 0.04419417382415922f;  // 1/sqrt(512)
  const dim3 blk(256);

  // 0. X -> bf16 once; weights -> bf16 B^T (QKV fused; Wd contiguous after)
  x_to_bf16<<<4000, blk, 0, stream>>>(X, Xbf);
  transpose_wqkv<<<dim3(32, 24), blk, 0, stream>>>(Wq, Wk, Wv, Wqkvt);
  transpose_w<<<dim3(2, 8), blk, 0, stream>>>(Wd, Wdt, 512, 128);
  // 1. fused QKV + hs projection (balanced 1D grid, BK=64)
  gemm_qkvh<<<6125, blk, 0, stream>>>(Xbf, Wqkvt, bq, bk, bv, bd,
                                      Q, K, V, hs, scale);
  // 2. LN on K and V rows (contiguous -> single launch); hs denominators
  hipMemsetAsync(d_out, 0, BB * HNL * sizeof(float), stream);
  ln2048_bf16<<<2 * MMR, blk, 0, stream>>>(K, lnl_g, lnl_b);
  hs_colsum<<<BB * 100, blk, 0, stream>>>(hs, mask, Ssum);
  // 3. landmark compression via MFMA
  hipMemsetAsync(ws + 204800000, 0, 4194304, stream);
  compress_mfma<<<1024, blk, 0, stream>>>(K, V, hs, mask, Ssum, Kc, Vc);
  // 4. LN on compressed rows (merged) -> KcB (row) and VcT (transposed)
  ln_comp_both<<<512, blk, 0, stream>>>(Kc, Vc, lns_g, lns_b, KcB, VcT);
  // 5. fused MFMA attention v4 (writes C = alias of Q)
  attn_mfma4<<<BB * HHN * 100, blk, 0, stream>>>(Q, K, V, KcB, VcT, mask, C);
  // 6. transpose Wo into dead K region, then output projection (MFMA, BK=32 control)
  transpose_w<<<dim3(8, 32), blk, 0, stream>>>(Wo, Wot, 2048, 512);
  gemm_bf16<float><<<dim3(4, 125), blk, 0, stream>>>(C, Wot, bo, out, MMR, 512, 2048, 1.f);
}

// Round 12
// 507.414 us; speedup vs baseline: 1.0204x; 1.0204x over previous
//
#include <hip/hip_runtime.h>
#include <math.h>

#define BB 8
#define SS 2000
#define DMM 512
#define HHN 4
#define DKK 512
#define HDK 2048
#define NLL 32
#define HNL 128
#define GGN 200
#define WSZ 10
#define TTN 20
#define EXTT 5
#define MMR (BB*SS)   // 16000

typedef unsigned short bf16_t;
typedef __attribute__((ext_vector_type(8))) short short8;
typedef __attribute__((ext_vector_type(4))) float floatx4;

// async global->LDS, 16B per lane. LDS dest must be wave-uniform-base + lane*16
// (linear); any swizzle must be applied to the GLOBAL source address.
#define GLL16(gp, lp) __builtin_amdgcn_global_load_lds( \
    (__attribute__((address_space(1))) void*)(gp), \
    (__attribute__((address_space(3))) void*)(lp), 16, 0, 0)

__device__ __forceinline__ float bf2f(bf16_t u) {
  union { unsigned u; float f; } x; x.u = ((unsigned)u) << 16; return x.f;
}
__device__ __forceinline__ bf16_t f2bf(float f) {
  union { float f; unsigned u; } x; x.f = f;
  unsigned r = x.u + 0x7FFFu + ((x.u >> 16) & 1u);
  return (bf16_t)(r >> 16);
}

// ---------------- block reduction helper (256 threads) ----------------
__device__ __forceinline__ float block_sum256(float v, float* sh) {
  #pragma unroll
  for (int off = 32; off > 0; off >>= 1) v += __shfl_down(v, off);
  if ((threadIdx.x & 63) == 0) sh[threadIdx.x >> 6] = v;
  __syncthreads();
  float t = sh[0] + sh[1] + sh[2] + sh[3];
  __syncthreads();
  return t;
}

// ---------------- X fp32 -> bf16 (once; feeds all projections) --------------
__global__ __launch_bounds__(256)
void x_to_bf16(const float* __restrict__ X, bf16_t* __restrict__ Xb) {
  int i = blockIdx.x * 256 + threadIdx.x;   // 8 elements per thread
  float4 a = *(const float4*)&X[(size_t)i * 8];
  float4 b = *(const float4*)&X[(size_t)i * 8 + 4];
  ushort4 u0, u1;
  u0.x = f2bf(a.x); u0.y = f2bf(a.y); u0.z = f2bf(a.z); u0.w = f2bf(a.w);
  u1.x = f2bf(b.x); u1.y = f2bf(b.y); u1.z = f2bf(b.z); u1.w = f2bf(b.w);
  *(ushort4*)&Xb[(size_t)i * 8] = u0;
  *(ushort4*)&Xb[(size_t)i * 8 + 4] = u1;
}

// ---------------- weight transpose fp32 -> bf16 B^T (generic) ---------------
__global__ __launch_bounds__(256)
void transpose_w(const float* __restrict__ W, bf16_t* __restrict__ Wt,
                 int K, int N) {
  __shared__ float Ts[64][65];
  int n0 = blockIdx.x * 64, k0 = blockIdx.y * 64;
  int tid = threadIdx.x;
  #pragma unroll
  for (int i = 0; i < 16; ++i) {
    int e = i * 256 + tid;
    int r = e >> 6, c = e & 63;
    Ts[r][c] = W[(size_t)(k0 + r) * N + n0 + c];
  }
  __syncthreads();
  #pragma unroll
  for (int i = 0; i < 16; ++i) {
    int e = i * 256 + tid;
    int r = e >> 6, c = e & 63;
    Wt[(size_t)(n0 + r) * K + k0 + c] = f2bf(Ts[c][r]);
  }
}

// ---------------- fused transpose of Wq|Wk|Wv into one [6144][512] B^T ------
// grid (32, 24): by selects source (by>>3) and k-chunk (by&7).
__global__ __launch_bounds__(256)
void transpose_wqkv(const float* __restrict__ Wq, const float* __restrict__ Wk,
                    const float* __restrict__ Wv, bf16_t* __restrict__ Wt) {
  __shared__ float Ts[64][65];
  int by = blockIdx.y;
  int which = by >> 3;
  const float* W = which == 0 ? Wq : (which == 1 ? Wk : Wv);
  int k0 = (by & 7) * 64;
  int n0 = blockIdx.x * 64;
  int tid = threadIdx.x;
  #pragma unroll
  for (int i = 0; i < 16; ++i) {
    int e = i * 256 + tid;
    int r = e >> 6, c = e & 63;
    Ts[r][c] = W[(size_t)(k0 + r) * 2048 + n0 + c];
  }
  __syncthreads();
  #pragma unroll
  for (int i = 0; i < 16; ++i) {
    int e = i * 256 + tid;
    int r = e >> 6, c = e & 63;
    Wt[(size_t)(which * 2048 + n0 + r) * 512 + k0 + c] = f2bf(Ts[c][r]);
  }
}

// ---------------- bf16 MFMA GEMM with global_load_lds staging (BK=32) -------
// Out = (A[M,K]bf16 @ Bt[N,K]^T + bias) * alpha. 128x128 tile.
// Staging: LDS linear (lane*16B); XOR swizzle sw=(row>>1)&3 on the GLOBAL
// source chunk (both-sides-or-neither). Bank-conflict-free (verified R6).
template <typename TO>
__global__ __launch_bounds__(256)
void gemm_bf16(const bf16_t* __restrict__ A, const bf16_t* __restrict__ Bt,
               const float* __restrict__ bias, TO* __restrict__ Cout,
               int M, int N, int K, float alpha) {
  __shared__ bf16_t As[128 * 32];
  __shared__ bf16_t Bs[128 * 32];
  int tid = threadIdx.x;
  int wave = tid >> 6, lane = tid & 63;
  int wr = wave >> 1, wc = wave & 1;
  int quad = lane >> 4, ml = lane & 15;
  int bm = blockIdx.y * 128, bn = blockIdx.x * 128;

  floatx4 acc[4][4];
  #pragma unroll
  for (int i = 0; i < 4; ++i)
    #pragma unroll
    for (int j = 0; j < 4; ++j)
      #pragma unroll
      for (int r = 0; r < 4; ++r) acc[i][j][r] = 0.f;

  int lin0 = wave * 64 + lane;
  int lin1 = 256 + lin0;
  int row0 = lin0 >> 2, ch0 = (lin0 & 3) ^ ((row0 >> 1) & 3);
  int row1 = lin1 >> 2, ch1 = (lin1 & 3) ^ ((row1 >> 1) & 3);
  const bf16_t* gA0 = &A[(size_t)(bm + row0) * K + ch0 * 8];
  const bf16_t* gA1 = &A[(size_t)(bm + row1) * K + ch1 * 8];
  const bf16_t* gB0 = &Bt[(size_t)(bn + row0) * K + ch0 * 8];
  const bf16_t* gB1 = &Bt[(size_t)(bn + row1) * K + ch1 * 8];

  for (int k0 = 0; k0 < K; k0 += 32) {
    GLL16(gA0 + k0, &As[lin0 * 8]);
    GLL16(gA1 + k0, &As[lin1 * 8]);
    GLL16(gB0 + k0, &Bs[lin0 * 8]);
    GLL16(gB1 + k0, &Bs[lin1 * 8]);
    __syncthreads();
    short8 af[4], bfr[4];
    #pragma unroll
    for (int i = 0; i < 4; ++i) {
      int row = wr * 64 + i * 16 + ml;
      int sw = quad ^ ((row >> 1) & 3);
      af[i] = *(const short8*)&As[row * 32 + sw * 8];
    }
    #pragma unroll
    for (int j = 0; j < 4; ++j) {
      int row = wc * 64 + j * 16 + ml;
      int sw = quad ^ ((row >> 1) & 3);
      bfr[j] = *(const short8*)&Bs[row * 32 + sw * 8];
    }
    #pragma unroll
    for (int i = 0; i < 4; ++i)
      #pragma unroll
      for (int j = 0; j < 4; ++j)
        acc[i][j] = __builtin_amdgcn_mfma_f32_16x16x32_bf16(af[i], bfr[j], acc[i][j], 0, 0, 0);
    __syncthreads();
  }
  #pragma unroll
  for (int i = 0; i < 4; ++i) {
    int row0o = bm + wr * 64 + i * 16 + quad * 4;
    #pragma unroll
    for (int j = 0; j < 4; ++j) {
      int col = bn + wc * 64 + j * 16 + ml;
      float bv = bias[col];
      #pragma unroll
      for (int r = 0; r < 4; ++r) {
        float o = (acc[i][j][r] + bv) * alpha;
        if constexpr (sizeof(TO) == 2)
          Cout[(size_t)(row0o + r) * N + col] = f2bf(o);
        else
          Cout[(size_t)(row0o + r) * N + col] = o;
      }
    }
  }
}

// ---------------- fused QKV + hs projection, BK=32, balanced 1D grid --------
// (R8 version restored — R9/R10's BK=64 regressed: VGPR 76->96, occupancy
// 32->21%, dur 157->166 us. In the 2-phase structure the barrier drain is
// hidden by resident waves; trading occupancy for barrier amortization loses.)
// Bt rows: 0..2047 Wq^T | 2048..4095 Wk^T | 4096..6143 Wv^T | 6144..6271 Wd^T.
// Grid = 6125 blocks, 1D: bid<6000 -> QKV (bx=bid%48, by=bid/48; 48%8==0
// keeps per-XCD B-panel L2 affinity); bid>=6000 -> hs row-blocks.
__global__ __launch_bounds__(256)
void gemm_qkvh(const bf16_t* __restrict__ A, const bf16_t* __restrict__ Bt,
               const float* __restrict__ bq, const float* __restrict__ bk,
               const float* __restrict__ bv, const float* __restrict__ bd,
               bf16_t* __restrict__ Qo, bf16_t* __restrict__ Ko,
               bf16_t* __restrict__ Vo, float* __restrict__ hso, float scale) {
  const int K = 512;
  __shared__ bf16_t As[128 * 32];
  __shared__ bf16_t Bs[128 * 32];
  int tid = threadIdx.x;
  int wave = tid >> 6, lane = tid & 63;
  int wr = wave >> 1, wc = wave & 1;
  int quad = lane >> 4, ml = lane & 15;

  int bid = blockIdx.x;
  int bm, bn;
  if (bid < 6000) {
    bn = (bid % 48) * 128;
    bm = (bid / 48) * 128;
  } else {
    bn = 6144;
    bm = (bid - 6000) * 128;
  }
  int nb = bn >> 11;
  const float* bias = nb == 0 ? bq : (nb == 1 ? bk : (nb == 2 ? bv : bd));
  bf16_t* Cb = nb == 0 ? Qo : (nb == 1 ? Ko : Vo);
  float alpha = nb == 0 ? scale : 1.f;
  int bcol = bn & 2047;

  floatx4 acc[4][4];
  #pragma unroll
  for (int i = 0; i < 4; ++i)
    #pragma unroll
    for (int j = 0; j < 4; ++j)
      #pragma unroll
      for (int r = 0; r < 4; ++r) acc[i][j][r] = 0.f;

  int lin0 = wave * 64 + lane;
  int lin1 = 256 + lin0;
  int row0 = lin0 >> 2, ch0 = (lin0 & 3) ^ ((row0 >> 1) & 3);
  int row1 = lin1 >> 2, ch1 = (lin1 & 3) ^ ((row1 >> 1) & 3);
  const bf16_t* gA0 = &A[(size_t)(bm + row0) * K + ch0 * 8];
  const bf16_t* gA1 = &A[(size_t)(bm + row1) * K + ch1 * 8];
  const bf16_t* gB0 = &Bt[(size_t)(bn + row0) * K + ch0 * 8];
  const bf16_t* gB1 = &Bt[(size_t)(bn + row1) * K + ch1 * 8];

  for (int k0 = 0; k0 < K; k0 += 32) {
    GLL16(gA0 + k0, &As[lin0 * 8]);
    GLL16(gA1 + k0, &As[lin1 * 8]);
    GLL16(gB0 + k0, &Bs[lin0 * 8]);
    GLL16(gB1 + k0, &Bs[lin1 * 8]);
    __syncthreads();
    short8 af[4], bfr[4];
    #pragma unroll
    for (int i = 0; i < 4; ++i) {
      int row = wr * 64 + i * 16 + ml;
      int sw = quad ^ ((row >> 1) & 3);
      af[i] = *(const short8*)&As[row * 32 + sw * 8];
    }
    #pragma unroll
    for (int j = 0; j < 4; ++j) {
      int row = wc * 64 + j * 16 + ml;
      int sw = quad ^ ((row >> 1) & 3);
      bfr[j] = *(const short8*)&Bs[row * 32 + sw * 8];
    }
    #pragma unroll
    for (int i = 0; i < 4; ++i)
      #pragma unroll
      for (int j = 0; j < 4; ++j)
        acc[i][j] = __builtin_amdgcn_mfma_f32_16x16x32_bf16(af[i], bfr[j], acc[i][j], 0, 0, 0);
    __syncthreads();
  }
  #pragma unroll
  for (int i = 0; i < 4; ++i) {
    int row0o = bm + wr * 64 + i * 16 + quad * 4;
    #pragma unroll
    for (int j = 0; j < 4; ++j) {
      int col = bcol + wc * 64 + j * 16 + ml;
      float bv2 = bias[col];
      #pragma unroll
      for (int r = 0; r < 4; ++r) {
        float o = (acc[i][j][r] + bv2) * alpha;
        if (nb == 3) hso[(size_t)(row0o + r) * HNL + col] = o;
        else         Cb[(size_t)(row0o + r) * HDK + col] = f2bf(o);
      }
    }
  }
}

// ---------------- LayerNorm over bf16 rows of 2048 (in place) ---------------
// K and V are contiguous -> one launch with 2*MMR blocks covers both.
__global__ __launch_bounds__(256)
void ln2048_bf16(bf16_t* __restrict__ Y, const float* __restrict__ gam,
                 const float* __restrict__ bet) {
  __shared__ float sh[4];
  bf16_t* y = Y + (size_t)blockIdx.x * HDK;
  int t = threadIdx.x;
  ushort4 ra = *(const ushort4*)&y[t * 8];
  ushort4 rb = *(const ushort4*)&y[t * 8 + 4];
  float v[8];
  v[0] = bf2f(ra.x); v[1] = bf2f(ra.y); v[2] = bf2f(ra.z); v[3] = bf2f(ra.w);
  v[4] = bf2f(rb.x); v[5] = bf2f(rb.y); v[6] = bf2f(rb.z); v[7] = bf2f(rb.w);
  float s = 0.f;
  #pragma unroll
  for (int j = 0; j < 8; ++j) s += v[j];
  s = block_sum256(s, sh);
  float mean = s * (1.f / 2048.f);
  float ss = 0.f;
  #pragma unroll
  for (int j = 0; j < 8; ++j) { float d = v[j] - mean; ss = fmaf(d, d, ss); }
  ss = block_sum256(ss, sh);
  float rstd = rsqrtf(ss * (1.f / 2048.f) + 1e-5f);
  float gg[8], bb[8];
  *(float4*)&gg[0] = *(const float4*)&gam[t * 8];
  *(float4*)&gg[4] = *(const float4*)&gam[t * 8 + 4];
  *(float4*)&bb[0] = *(const float4*)&bet[t * 8];
  *(float4*)&bb[4] = *(const float4*)&bet[t * 8 + 4];
  ushort4 oa, ob;
  oa.x = f2bf((v[0] - mean) * rstd * gg[0] + bb[0]);
  oa.y = f2bf((v[1] - mean) * rstd * gg[1] + bb[1]);
  oa.z = f2bf((v[2] - mean) * rstd * gg[2] + bb[2]);
  oa.w = f2bf((v[3] - mean) * rstd * gg[3] + bb[3]);
  ob.x = f2bf((v[4] - mean) * rstd * gg[4] + bb[4]);
  ob.y = f2bf((v[5] - mean) * rstd * gg[5] + bb[5]);
  ob.z = f2bf((v[6] - mean) * rstd * gg[6] + bb[6]);
  ob.w = f2bf((v[7] - mean) * rstd * gg[7] + bb[7]);
  *(ushort4*)&y[t * 8] = oa;
  *(ushort4*)&y[t * 8 + 4] = ob;
}

// ---------------- column sums of exp(hs) over valid s -----------------------
__global__ __launch_bounds__(256)
void hs_colsum(const float* __restrict__ hs, const float* __restrict__ mask,
               float* __restrict__ Ssum) {
  __shared__ float red[128];
  int b = blockIdx.x / 100;
  int chunk = blockIdx.x % 100;
  int tid = threadIdx.x;
  int c = tid & 127, half = tid >> 7;
  int s0 = chunk * 20;
  float sum = 0.f;
  #pragma unroll
  for (int i = 0; i < 10; ++i) {
    int s = s0 + i * 2 + half;
    float m = mask[(size_t)b * SS + s];
    float v = hs[((size_t)b * SS + s) * HNL + c];
    sum += (m != 0.f) ? __expf(v) : 0.f;
  }
  if (half == 1) red[c] = sum;
  __syncthreads();
  if (half == 0) atomicAdd(&Ssum[b * HNL + c], sum + red[c]);
}

// ---------------- landmark compression via MFMA -----------------------------
__global__ __launch_bounds__(256)
void compress_mfma(const bf16_t* __restrict__ Kf, const bf16_t* __restrict__ Vf,
                   const float* __restrict__ hs, const float* __restrict__ mask,
                   const float* __restrict__ Ssum, float* __restrict__ Kc,
                   float* __restrict__ Vc) {
  int dch = blockIdx.x & 3;
  int sch = (blockIdx.x >> 2) & 7;
  int bh  = blockIdx.x >> 5;
  int h = bh & 3, b = bh >> 2;
  int sbase = sch * 250;
  int dbase = dch * 128;

  __shared__ __align__(16) bf16_t Ah[32 * 40];
  __shared__ __align__(16) bf16_t Kt[128 * 40];
  __shared__ __align__(16) bf16_t Vt[128 * 40];

  int tid = threadIdx.x;
  int wave = tid >> 6, lane = tid & 63;
  int tensor = wave >> 1, nh = wave & 1;
  int quad = lane >> 4, ml = lane & 15;

  float inv8[8];
  if (tid < 128) {
    int l0 = (tid & 3) * 8;
    #pragma unroll
    for (int j = 0; j < 8; ++j)
      inv8[j] = 1.f / Ssum[b * HNL + h * NLL + l0 + j];
  }

  floatx4 acc[2][4];
  #pragma unroll
  for (int i = 0; i < 2; ++i)
    #pragma unroll
    for (int j = 0; j < 4; ++j)
      #pragma unroll
      for (int r = 0; r < 4; ++r) acc[i][j][r] = 0.f;

  for (int ks = 0; ks < 8; ++ks) {
    int s0 = ks * 32;
    if (tid < 128) {
      int si = tid >> 2;
      int l0 = (tid & 3) * 8;
      int s_l = s0 + si;
      float w[8];
      #pragma unroll
      for (int j = 0; j < 8; ++j) w[j] = 0.f;
      if (s_l < 250) {
        float m = mask[(size_t)b * SS + sbase + s_l];
        if (m != 0.f) {
          const float* p = &hs[((size_t)b * SS + sbase + s_l) * HNL + h * NLL + l0];
          float4 f0 = *(const float4*)p;
          float4 f1 = *(const float4*)(p + 4);
          w[0] = __expf(f0.x) * inv8[0];
          w[1] = __expf(f0.y) * inv8[1];
          w[2] = __expf(f0.z) * inv8[2];
          w[3] = __expf(f0.w) * inv8[3];
          w[4] = __expf(f1.x) * inv8[4];
          w[5] = __expf(f1.y) * inv8[5];
          w[6] = __expf(f1.z) * inv8[6];
          w[7] = __expf(f1.w) * inv8[7];
        }
      }
      #pragma unroll
      for (int j = 0; j < 8; ++j)
        Ah[(l0 + j) * 40 + si] = f2bf(w[j]);
    }
    {
      int si = tid >> 3;
      int d0 = (tid & 7) * 16;
      int s_l = s0 + si;
      uint4 ka = {0, 0, 0, 0}, kb = {0, 0, 0, 0};
      uint4 va = {0, 0, 0, 0}, vb = {0, 0, 0, 0};
      if (s_l < 250) {
        size_t gof = ((size_t)b * SS + sbase + s_l) * HDK + h * DKK + dbase + d0;
        ka = *(const uint4*)&Kf[gof];
        kb = *(const uint4*)&Kf[gof + 8];
        va = *(const uint4*)&Vf[gof];
        vb = *(const uint4*)&Vf[gof + 8];
      }
      const ushort* kp = (const ushort*)&ka;
      const ushort* kq = (const ushort*)&kb;
      const ushort* vp = (const ushort*)&va;
      const ushort* vq = (const ushort*)&vb;
      #pragma unroll
      for (int j = 0; j < 8; ++j) {
        Kt[(d0 + j) * 40 + si]     = kp[j];
        Kt[(d0 + 8 + j) * 40 + si] = kq[j];
        Vt[(d0 + j) * 40 + si]     = vp[j];
        Vt[(d0 + 8 + j) * 40 + si] = vq[j];
      }
    }
    __syncthreads();
    const bf16_t* Bsel = tensor ? Vt : Kt;
    #pragma unroll
    for (int i = 0; i < 2; ++i) {
      short8 af = *(const short8*)&Ah[(i * 16 + ml) * 40 + quad * 8];
      #pragma unroll
      for (int j = 0; j < 4; ++j) {
        short8 bfr = *(const short8*)&Bsel[(nh * 64 + j * 16 + ml) * 40 + quad * 8];
        acc[i][j] = __builtin_amdgcn_mfma_f32_16x16x32_bf16(af, bfr, acc[i][j], 0, 0, 0);
      }
    }
    __syncthreads();
  }
  float* outp = tensor ? Vc : Kc;
  size_t obase = ((size_t)b * 4 + h) * (NLL * DKK);
  #pragma unroll
  for (int i = 0; i < 2; ++i) {
    #pragma unroll
    for (int j = 0; j < 4; ++j) {
      int d = dbase + nh * 64 + j * 16 + ml;
      #pragma unroll
      for (int r = 0; r < 4; ++r) {
        int l = i * 16 + quad * 4 + r;
        atomicAdd(&outp[obase + (size_t)l * DKK + d], acc[i][j][r]);
      }
    }
  }
}

// ---------------- LN on Kc AND Vc rows (merged), bf16 out -------------------
__global__ __launch_bounds__(256)
void ln_comp_both(const float* __restrict__ Kc, const float* __restrict__ Vc,
                  const float* __restrict__ gam, const float* __restrict__ bet,
                  bf16_t* __restrict__ KcB, bf16_t* __restrict__ VcT) {
  __shared__ float sh[4];
  int which = blockIdx.x >> 8;
  int bid = blockIdx.x & 255;
  const float* Y = which ? Vc : Kc;
  bf16_t* outp = which ? VcT : KcB;
  int b = bid >> 5, l = bid & 31;
  size_t base = (size_t)b * 65536 + (size_t)l * 512;
  float v[8]; float s = 0.f;
  #pragma unroll
  for (int j = 0; j < 8; ++j) {
    int f = threadIdx.x + 256 * j;
    int hh = f >> 9, dd = f & 511;
    v[j] = Y[base + (size_t)hh * 16384 + dd];
    s += v[j];
  }
  s = block_sum256(s, sh);
  float mean = s * (1.f / 2048.f);
  float ss = 0.f;
  #pragma unroll
  for (int j = 0; j < 8; ++j) { float d = v[j] - mean; ss = fmaf(d, d, ss); }
  ss = block_sum256(ss, sh);
  float rstd = rsqrtf(ss * (1.f / 2048.f) + 1e-5f);
  #pragma unroll
  for (int j = 0; j < 8; ++j) {
    int f = threadIdx.x + 256 * j;
    int hh = f >> 9, dd = f & 511;
    float o = (v[j] - mean) * rstd * gam[f] + bet[f];
    if (!which)
      outp[(((size_t)b * 4 + hh) * 32 + l) * 512 + dd] = f2bf(o);
    else
      outp[(((size_t)b * 4 + hh) * 512 + dd) * 32 + l] = f2bf(o);
  }
}

// ---------------- MFMA fused attention v4: no transpose buffer --------------
__global__ __launch_bounds__(256)
void attn_mfma4(const bf16_t* __restrict__ Qf, const bf16_t* __restrict__ Kf,
                const bf16_t* __restrict__ Vf, const bf16_t* __restrict__ KcB,
                const bf16_t* __restrict__ VcT, const float* __restrict__ mask,
                bf16_t* __restrict__ Cf) {
  int gp = blockIdx.x % 100;
  int bh = blockIdx.x / 100;
  int h = bh & 3, b = bh >> 2;
  int g0row = gp * 20;
  int wbase = g0row - EXTT;

  __shared__ bf16_t Vst[30 * 128];   //  7680 B, chunk-swizzled
  __shared__ float  sc[20][68];      //  5440 B raw scores
  __shared__ bf16_t Ps[32 * 88];     //  5632 B bf16 probs (compress|window)
  __shared__ float  cv[32];          //  total ~18.9 KB -> 8 blocks/CU

  int tid = threadIdx.x;
  int wave = tid >> 6, lane = tid & 63;
  int quad = lane >> 4, ml = lane & 15;

  if (tid < 30) {
    int j = wbase + tid;
    cv[tid] = (j >= 0 && j < SS && mask[(size_t)b * SS + j] != 0.f) ? 1.f : 0.f;
  }
  for (int i = tid; i < 32 * 88; i += 256) Ps[i] = 0;

  // ---- scores: direct-global MFMA ----
  int qr0 = g0row + (ml < 20 ? ml : 19);
  int r1c = 16 + ml;
  int qr1 = g0row + (r1c < 20 ? r1c : 19);
  const bf16_t* ap0 = Qf + ((size_t)b * SS + qr0) * HDK + h * DKK;
  const bf16_t* ap1 = Qf + ((size_t)b * SS + qr1) * HDK + h * DKK;
  int brow = wave * 16 + ml;
  const bf16_t* bp;
  if (brow < 32) {
    bp = KcB + ((size_t)bh * 32 + brow) * 512;
  } else {
    int j = wbase + brow - 32;
    j = j < 0 ? 0 : (j >= SS ? SS - 1 : j);
    bp = Kf + ((size_t)b * SS + j) * HDK + h * DKK;
  }
  floatx4 s0 = {0.f, 0.f, 0.f, 0.f}, s1 = {0.f, 0.f, 0.f, 0.f};
  #pragma unroll 8
  for (int ks = 0; ks < 16; ++ks) {
    short8 af0 = *(const short8*)(ap0 + ks * 32 + quad * 8);
    short8 af1 = *(const short8*)(ap1 + ks * 32 + quad * 8);
    short8 bfr = *(const short8*)(bp  + ks * 32 + quad * 8);
    s0 = __builtin_amdgcn_mfma_f32_16x16x32_bf16(af0, bfr, s0, 0, 0, 0);
    s1 = __builtin_amdgcn_mfma_f32_16x16x32_bf16(af1, bfr, s1, 0, 0, 0);
  }
  #pragma unroll
  for (int r = 0; r < 4; ++r) {
    int row0 = quad * 4 + r;
    if (row0 < 20) sc[row0][wave * 16 + ml] = s0[r];
    int row1 = 16 + quad * 4 + r;
    if (row1 < 20) sc[row1][wave * 16 + ml] = s1[r];
  }

  // ---- V chunk 0 prefetch (overlaps barrier + softmax) ----
  uint4 vr[2];
  #pragma unroll
  for (int vi = 0; vi < 2; ++vi) {
    int idx = vi * 256 + tid;
    uint4 z = {0, 0, 0, 0};
    if (idx < 480) {
      int u = idx >> 4, c8 = idx & 15;
      int j = wbase + u;
      if (j >= 0 && j < SS)
        z = *(const uint4*)&Vf[((size_t)b * SS + j) * HDK + h * DKK + c8 * 8];
    }
    vr[vi] = z;
  }
  __syncthreads();   // B1: sc, Ps-zero, cv visible

  // ---- softmax: 160 threads, 8 per row ----
  if (tid < 160) {
    int r = tid >> 3, part = tid & 7;
    float mx = -INFINITY;
    #pragma unroll
    for (int i = 0; i < 8; ++i) {
      int c = part + i * 8;
      if (c < 62) {
        float v = sc[r][c];
        bool valid;
        if (c < 32) valid = true;
        else {
          int u = c - 32;
          valid = (u < 30) && (cv[u] != 0.f) && (r < 10 ? (u < 20) : (u >= 10));
        }
        v = valid ? v : -INFINITY;
        sc[r][c] = v;
        mx = fmaxf(mx, v);
      }
    }
    mx = fmaxf(mx, __shfl_xor(mx, 1));
    mx = fmaxf(mx, __shfl_xor(mx, 2));
    mx = fmaxf(mx, __shfl_xor(mx, 4));
    float sum = 0.f;
    #pragma unroll
    for (int i = 0; i < 8; ++i) {
      int c = part + i * 8;
      if (c < 62) {
        float e = expf(sc[r][c] - mx);
        sc[r][c] = e;
        sum += e;
      }
    }
    sum += __shfl_xor(sum, 1);
    sum += __shfl_xor(sum, 2);
    sum += __shfl_xor(sum, 4);
    float qm = mask[(size_t)b * SS + g0row + r];
    float inv = (qm != 0.f) ? 1.f / sum : 0.f;
    #pragma unroll
    for (int i = 0; i < 8; ++i) {
      int c = part + i * 8;
      if (c < 62) {
        float p = sc[r][c] * inv;
        if (c < 32) Ps[r * 88 + c] = f2bf(p);
        else        Ps[r * 88 + 40 + (c - 32)] = f2bf(p);
      }
    }
  }
  // write Vst chunk 0 (swizzled slots)
  #pragma unroll
  for (int vi = 0; vi < 2; ++vi) {
    int idx = vi * 256 + tid;
    if (idx < 480) {
      int u = idx >> 4, c8 = idx & 15;
      int slot = c8 ^ ((u >> 3) & 3);
      *(uint4*)&Vst[u * 128 + slot * 8] = vr[vi];
    }
  }
  __syncthreads();   // B2: Vst0 ready, softmax done

  // ---- P fragments (persist across chunks) ----
  short8 pac0 = *(const short8*)&Ps[ml * 88 + quad * 8];
  short8 pac1 = *(const short8*)&Ps[(16 + ml) * 88 + quad * 8];
  short8 paw0 = *(const short8*)&Ps[ml * 88 + 40 + quad * 8];
  short8 paw1 = *(const short8*)&Ps[(16 + ml) * 88 + 40 + quad * 8];
  size_t vctbase = ((size_t)bh * 512) * 32;
  size_t cbase = ((size_t)b * SS + g0row) * HDK + h * DKK;

  // ---- chunked PV straight from swizzled Vst columns ----
  #pragma unroll
  for (int ch = 0; ch < 4; ++ch) {
    int dA = ch * 128 + (wave * 2 + 0) * 16 + ml;
    int dB = ch * 128 + (wave * 2 + 1) * 16 + ml;
    short8 vcfA = *(const short8*)&VcT[vctbase + (size_t)dA * 32 + quad * 8];
    short8 vcfB = *(const short8*)&VcT[vctbase + (size_t)dB * 32 + quad * 8];
    if (ch < 3) {
      #pragma unroll
      for (int vi = 0; vi < 2; ++vi) {
        int idx = vi * 256 + tid;
        uint4 z = {0, 0, 0, 0};
        if (idx < 480) {
          int u = idx >> 4, c8 = idx & 15;
          int j = wbase + u;
          if (j >= 0 && j < SS)
            z = *(const uint4*)&Vf[((size_t)b * SS + j) * HDK + h * DKK + (ch + 1) * 128 + c8 * 8];
        }
        vr[vi] = z;
      }
    }

    #pragma unroll
    for (int half = 0; half < 2; ++half) {
      int dl = (wave * 2 + half) * 16 + ml;     // 0..127 within chunk
      int d = ch * 128 + dl;
      int cd = dl >> 3, de = dl & 7;
      short8 vwf;
      #pragma unroll
      for (int j = 0; j < 8; ++j) {
        int u = quad * 8 + j;                   // t index 0..31
        bf16_t x = 0;
        if (u < 30) {
          int slot = cd ^ ((u >> 3) & 3);
          x = Vst[u * 128 + slot * 8 + de];
        }
        vwf[j] = (short)x;
      }
      short8 vcf = half ? vcfB : vcfA;
      floatx4 o0 = {0.f, 0.f, 0.f, 0.f}, o1 = {0.f, 0.f, 0.f, 0.f};
      o0 = __builtin_amdgcn_mfma_f32_16x16x32_bf16(pac0, vcf, o0, 0, 0, 0);
      o0 = __builtin_amdgcn_mfma_f32_16x16x32_bf16(paw0, vwf, o0, 0, 0, 0);
      o1 = __builtin_amdgcn_mfma_f32_16x16x32_bf16(pac1, vcf, o1, 0, 0, 0);
      o1 = __builtin_amdgcn_mfma_f32_16x16x32_bf16(paw1, vwf, o1, 0, 0, 0);
      #pragma unroll
      for (int r = 0; r < 4; ++r) {
        int row0 = quad * 4 + r;
        if (row0 < 20) Cf[cbase + (size_t)row0 * HDK + d] = f2bf(o0[r]);
        int row1 = 16 + quad * 4 + r;
        if (row1 < 20) Cf[cbase + (size_t)row1 * HDK + d] = f2bf(o1[r]);
      }
    }
    __syncthreads();                   // PV(ch) done reading Vst
    if (ch < 3) {
      #pragma unroll
      for (int vi = 0; vi < 2; ++vi) {
        int idx = vi * 256 + tid;
        if (idx < 480) {
          int u = idx >> 4, c8 = idx & 15;
          int slot = c8 ^ ((u >> 3) & 3);
          *(uint4*)&Vst[u * 128 + slot * 8] = vr[vi];
        }
      }
      __syncthreads();                 // Vst(ch+1) ready
    }
  }
}

extern "C" void kernel_launch(void* const* d_in, const int* in_sizes, int n_in,
                              void* d_out, int out_size, void* d_ws, size_t ws_size,
                              hipStream_t stream) {
  const float* X     = (const float*)d_in[0];
  const float* mask  = (const float*)d_in[3];
  const float* Wq    = (const float*)d_in[4];
  const float* bq    = (const float*)d_in[5];
  const float* Wk    = (const float*)d_in[6];
  const float* bk    = (const float*)d_in[7];
  const float* Wv    = (const float*)d_in[8];
  const float* bv    = (const float*)d_in[9];
  const float* Wo    = (const float*)d_in[10];
  const float* bo    = (const float*)d_in[11];
  const float* Wd    = (const float*)d_in[12];
  const float* bd    = (const float*)d_in[13];
  const float* lnl_g = (const float*)d_in[14];
  const float* lnl_b = (const float*)d_in[15];
  const float* lns_g = (const float*)d_in[16];
  const float* lns_b = (const float*)d_in[17];
  float* out = (float*)d_out;

  // workspace carve (bytes): total ~209 MB
  char* ws = (char*)d_ws;
  bf16_t* Q   = (bf16_t*)(ws);                 // 65,536,000 B
  bf16_t* K   = (bf16_t*)(ws + 65536000);      // 65,536,000 B (V follows -> contiguous for merged LN)
  bf16_t* V   = (bf16_t*)(ws + 131072000);     // 65,536,000 B
  float*  hs  = (float*) (ws + 196608000);     // 8,192,000 B (raw, no softmax)
  float*  Kc  = (float*) (ws + 204800000);     // 2,097,152 B
  float*  Vc  = (float*) (ws + 206897152);     // 2,097,152 B
  bf16_t* C   = Q;                             // alias (see attn_mfma4 note)
  bf16_t* Wot = (bf16_t*)(ws + 65536000);      // K region (post-attn)
  // bf16 LN'd compress tensors in hs region (hs dead after compress).
  bf16_t* KcB = (bf16_t*)(ws + 196608000);            // 1,048,576 B
  bf16_t* VcT = (bf16_t*)(ws + 196608000 + 1048576);  // 1,048,576 B
  // d_out scratch (all dead before the final out-projection writes d_out):
  float*  Ssum  = (float*)d_out;                        // 4 KB at offset 0
  bf16_t* Xbf   = (bf16_t*)((char*)d_out + 65536);      // 16,384,000 B
  bf16_t* Wqkvt = (bf16_t*)((char*)d_out + 16449536);   // 6,291,456 B [6144][512]
  bf16_t* Wdt   = (bf16_t*)((char*)d_out + 22740992);   // 131,072 B, = Wqkvt rows 6144..6271
  // (ends at 22,872,064 < out_size 32,768,000)

  const float scale = 0.04419417382415922f;  // 1/sqrt(512)
  const dim3 blk(256);

  // 0. X -> bf16 once; weights -> bf16 B^T (QKV fused; Wd contiguous after)
  x_to_bf16<<<4000, blk, 0, stream>>>(X, Xbf);
  transpose_wqkv<<<dim3(32, 24), blk, 0, stream>>>(Wq, Wk, Wv, Wqkvt);
  transpose_w<<<dim3(2, 8), blk, 0, stream>>>(Wd, Wdt, 512, 128);
  // 1. fused QKV + hs projection (balanced 1D grid, BK=32 — R8 best config)
  gemm_qkvh<<<6125, blk, 0, stream>>>(Xbf, Wqkvt, bq, bk, bv, bd,
                                      Q, K, V, hs, scale);
  // 2. LN on K and V rows (contiguous -> single launch); hs denominators
  hipMemsetAsync(d_out, 0, BB * HNL * sizeof(float), stream);
  ln2048_bf16<<<2 * MMR, blk, 0, stream>>>(K, lnl_g, lnl_b);
  hs_colsum<<<BB * 100, blk, 0, stream>>>(hs, mask, Ssum);
  // 3. landmark compression via MFMA
  hipMemsetAsync(ws + 204800000, 0, 4194304, stream);
  compress_mfma<<<1024, blk, 0, stream>>>(K, V, hs, mask, Ssum, Kc, Vc);
  // 4. LN on compressed rows (merged) -> KcB (row) and VcT (transposed)
  ln_comp_both<<<512, blk, 0, stream>>>(Kc, Vc, lns_g, lns_b, KcB, VcT);
  // 5. fused MFMA attention v4 (writes C = alias of Q)
  attn_mfma4<<<BB * HHN * 100, blk, 0, stream>>>(Q, K, V, KcB, VcT, mask, C);
  // 6. transpose Wo into dead K region, then output projection (MFMA)
  transpose_w<<<dim3(8, 32), blk, 0, stream>>>(Wo, Wot, 2048, 512);
  gemm_bf16<float><<<dim3(4, 125), blk, 0, stream>>>(C, Wot, bo, out, MMR, 512, 2048, 1.f);
}